// Round 7
// baseline (356.918 us; speedup 1.0000x reference)
//
#include <hip/hip_runtime.h>
#include <stdint.h>
#include <stddef.h>

#define BB 32
#define PP 9045
#define FF 750
#define MM (BB*PP)        // 289440 rows
#define NT16 (MM/16)      // 18090 16-row tiles (exact)
#define NBLK2 512         // k_sim grid: 512 blocks x 256 thr (2 blocks/CU)

typedef float  f32x4  __attribute__((ext_vector_type(4)));
typedef short  s16x8  __attribute__((ext_vector_type(8)));
typedef unsigned int u32x4v __attribute__((ext_vector_type(4)));

typedef const __attribute__((address_space(1))) void* gp1;
typedef __attribute__((address_space(3))) void* sp3;
typedef __attribute__((address_space(3))) unsigned char* sp3c;

__device__ __forceinline__ unsigned rne_bf16(float f){
    unsigned u = __builtin_bit_cast(unsigned, f);
    return (u + 0x7fffu + ((u >> 16) & 1u)) >> 16;   // round-to-nearest-even
}
__device__ __forceinline__ unsigned pack2(float lo, float hi){
    return rne_bf16(lo) | (rne_bf16(hi) << 16);
}
__device__ __forceinline__ unsigned cvtpk(float lo, float hi){
    unsigned r;
    asm volatile("v_cvt_pk_bf16_f32 %0, %1, %2" : "=v"(r) : "v"(lo), "v"(hi));
    return r;
}
__device__ __forceinline__ float tanh_fast(float v){
    return 1.f - 2.f / (1.f + __expf(2.f * v));
}

// ---------------- K0: pre-pack sw1 (750x32 f32) into MFMA B-fragment layout -----------
__global__ void k_w1f(const float* __restrict__ sw1, u32x4v* __restrict__ w1f){
    int t = blockIdx.x * blockDim.x + threadIdx.x;   // 0..3071
    if (t >= 24*2*64) return;
    int lane = t & 63, nt = (t >> 6) & 1, s = t >> 7;
    int col = nt*16 + (lane & 15);
    int kb  = s*32 + ((lane >> 4) << 3);
    float v[8];
    #pragma unroll
    for (int e = 0; e < 8; ++e){ int k = kb + e; v[e] = (k < FF) ? sw1[k*32 + col] : 0.f; }
    u32x4v o;
    o.x = pack2(v[0],v[1]); o.y = pack2(v[2],v[3]);
    o.z = pack2(v[4],v[5]); o.w = pack2(v[6],v[7]);
    w1f[t] = o;
}

// ---------------- KA: fused similarity MLP, 4 waves cooperate on one 16-row tile ------
// Tile = contiguous 48000 B of x, staged LINEARLY by 47 global_load_lds builtins
// (compiler-tracked vmem; interleaved j%4==w across waves -> one near-linear block
// stream). K-split: wave w computes k-steps [6w,6w+6) with 48 static VGPRs of w1f
// (plain C loads, no raw-asm globals anywhere). Partial accs combined via LDS;
// wave 0 runs the epilogue. Sync = vmcnt(0)+__syncthreads, 2 barriers/tile.
__global__ __launch_bounds__(256) void k_sim(
    const float* __restrict__ x, const u32x4v* __restrict__ w1f,
    const float* __restrict__ sb1,
    const float* __restrict__ sw2, const float* __restrict__ sb2,
    const float* __restrict__ sw3, const float* __restrict__ sb3,
    const float* __restrict__ sw4, const float* __restrict__ sb4,
    float* __restrict__ simT)
{
    // [0,48128) tile | [48128,50176) h1 | [50176,52224) h2 | [52224,58368) acc-exchange
    __shared__ __attribute__((aligned(16))) unsigned char scratch[58368];
    const int tid  = threadIdx.x;
    const int w    = tid >> 6;       // wave 0..3 (k-slice owner)
    const int lane = tid & 63;
    const int g = lane >> 4;         // k-group within a k-step
    const int c = lane & 15;         // row (A) / col (B,D)

    // ---- static per-wave w1f fragments: 6 k-steps x 2 n-halves (48 VGPRs) ----
    u32x4v WA[6], WB[6];
    #pragma unroll
    for (int i = 0; i < 6; ++i){
        int s = 6*w + i;
        WA[i] = w1f[(2*s+0)*64 + lane];
        WB[i] = w1f[(2*s+1)*64 + lane];
    }

    // ---- epilogue constants (used by wave 0; loaded uniformly) ----
    u32x4v t2, t3;
    {
        float v[8];
        #pragma unroll
        for (int e = 0; e < 8; ++e) v[e] = sw2[(8*g+e)*16 + c];          // sw2: [32][16]
        t2.x = pack2(v[0],v[1]); t2.y = pack2(v[2],v[3]);
        t2.z = pack2(v[4],v[5]); t2.w = pack2(v[6],v[7]);
        #pragma unroll
        for (int e = 0; e < 8; ++e){
            int k = 8*g+e;
            v[e] = (k < 16 && c < 8) ? sw3[k*8 + c] : 0.f;               // sw3: [16][8]
        }
        t3.x = pack2(v[0],v[1]); t3.y = pack2(v[2],v[3]);
        t3.z = pack2(v[4],v[5]); t3.w = pack2(v[6],v[7]);
    }
    const s16x8 w2f = __builtin_bit_cast(s16x8, t2);
    const s16x8 w3f = __builtin_bit_cast(s16x8, t3);
    const float w4c  = (c < 8) ? sw4[c] : 0.f;
    const float sb4v = sb4[0];
    const float b2c  = sb2[c];
    const float b3c  = (c < 8) ? sb3[c] : 0.f;
    const float b1lo = sb1[c], b1hi = sb1[16+c];

    {   // h2 pad cols (16..31) must read 0 in layer 3; never written elsewhere
        unsigned short* h2z = (unsigned short*)(scratch + 50176);
        for (int i = tid; i < 640; i += 256) h2z[i] = 0;
    }

    const uint32_t lbase = (uint32_t)(uintptr_t)(sp3c)scratch;
    const uint32_t rB = lbase + 3000u*(uint32_t)c + 32u*(uint32_t)g;

    // stage: wave w issues glls j = w, w+4, ... (<47); LDS dest linear, src linear
#define STAGEW(BASE) do{ \
    for (int j_ = w; j_ < 47; j_ += 4) \
        __builtin_amdgcn_global_load_lds((gp1)((BASE) + 1024*j_ + 16*lane), \
            (sp3)(scratch + 1024*j_), 16, 0, 0); \
}while(0)

    const char* cur = (const char*)x + 48000ull * (unsigned)blockIdx.x;

    STAGEW(cur);
    asm volatile("s_waitcnt vmcnt(0)" ::: "memory");
    __syncthreads();   // tile 0 staged (also covers h2z init)

    for (int t = blockIdx.x; t < NT16; t += NBLK2){
        const char* nxt = cur + 48000ull * NBLK2;
        const bool  pf  = (t + NBLK2 < NT16);
        const int   r0  = t << 4;

        // ---- compute own 6 k-steps (no vmem waits needed: buffer complete) ----
        f32x4 D0[6], D1[6];
        #pragma unroll
        for (int i = 0; i < 6; ++i){
            uint32_t ad = rB + 128u*(uint32_t)(6*w + i);
            asm volatile("ds_read_b128 %0, %1"           : "=&v"(D0[i]) : "v"(ad));
            asm volatile("ds_read_b128 %0, %1 offset:16" : "=&v"(D1[i]) : "v"(ad));
        }
        asm volatile("s_waitcnt lgkmcnt(0)" ::: "memory");
        __builtin_amdgcn_sched_barrier(0);
        if (w == 3){   // ks=23 covers k 736..767; k>=750 is garbage -> zero
            if (g >= 2){ D0[5] = (f32x4){0.f,0.f,0.f,0.f}; D1[5] = (f32x4){0.f,0.f,0.f,0.f}; }
            else if (g == 1){ D1[5][2] = 0.f; D1[5][3] = 0.f; }
        }
        f32x4 acc0, acc1;
        if (w == 0){ acc0 = (f32x4){b1lo,b1lo,b1lo,b1lo}; acc1 = (f32x4){b1hi,b1hi,b1hi,b1hi}; }
        else       { acc0 = (f32x4){0.f,0.f,0.f,0.f};     acc1 = (f32x4){0.f,0.f,0.f,0.f};     }
        #pragma unroll
        for (int i = 0; i < 6; ++i){
            u32x4v a_;
            a_.x = cvtpk(D0[i][0], D0[i][1]); a_.y = cvtpk(D0[i][2], D0[i][3]);
            a_.z = cvtpk(D1[i][0], D1[i][1]); a_.w = cvtpk(D1[i][2], D1[i][3]);
            s16x8 av = __builtin_bit_cast(s16x8, a_);
            acc0 = __builtin_amdgcn_mfma_f32_16x16x32_bf16(av, __builtin_bit_cast(s16x8, WA[i]), acc0, 0,0,0);
            acc1 = __builtin_amdgcn_mfma_f32_16x16x32_bf16(av, __builtin_bit_cast(s16x8, WB[i]), acc1, 0,0,0);
        }

        // ---- combine partials across waves ----
        if (w){
            float* cb = (float*)(scratch + 52224 + (unsigned)(w-1)*2048 + (unsigned)lane*32);
            *(f32x4*)cb       = acc0;
            *(f32x4*)(cb + 4) = acc1;
        }
        __syncthreads();   // partials visible; all waves done reading tile buffer

        if (w == 0){
            #pragma unroll
            for (int q = 0; q < 3; ++q){
                const float* cb = (const float*)(scratch + 52224 + (unsigned)q*2048 + (unsigned)lane*32);
                f32x4 p0 = *(const f32x4*)cb;
                f32x4 p1 = *(const f32x4*)(cb + 4);
                #pragma unroll
                for (int j = 0; j < 4; ++j){ acc0[j] += p0[j]; acc1[j] += p1[j]; }
            }
            // ---- layers 2/3/4 (h region disjoint from tile buffer) ----
            unsigned short* h1 = (unsigned short*)(scratch + 48128);
            unsigned short* h2 = (unsigned short*)(scratch + 50176);
            #pragma unroll
            for (int j = 0; j < 4; ++j){
                h1[(4*g+j)*40 + c]      = (unsigned short)rne_bf16(fmaxf(acc0[j], 0.f));
                h1[(4*g+j)*40 + 16 + c] = (unsigned short)rne_bf16(fmaxf(acc1[j], 0.f));
            }
            asm volatile("s_waitcnt lgkmcnt(0)" ::: "memory");   // same-wave LDS RAW
            __builtin_amdgcn_sched_barrier(0);
            s16x8 a2 = *reinterpret_cast<const s16x8*>(&h1[c*40 + 8*g]);
            f32x4 c2i = {b2c,b2c,b2c,b2c};
            f32x4 d2 = __builtin_amdgcn_mfma_f32_16x16x32_bf16(a2, w2f, c2i, 0,0,0);

            #pragma unroll
            for (int j = 0; j < 4; ++j)
                h2[(4*g+j)*40 + c] = (unsigned short)rne_bf16(fmaxf(d2[j], 0.f));
            asm volatile("s_waitcnt lgkmcnt(0)" ::: "memory");
            __builtin_amdgcn_sched_barrier(0);
            s16x8 a3 = *reinterpret_cast<const s16x8*>(&h2[c*40 + 8*g]);
            f32x4 c3i = {b3c,b3c,b3c,b3c};
            f32x4 d3 = __builtin_amdgcn_mfma_f32_16x16x32_bf16(a3, w3f, c3i, 0,0,0);

            #pragma unroll
            for (int j = 0; j < 4; ++j){
                float tt = fmaxf(d3[j], 0.f) * w4c;
                tt += __shfl_xor(tt, 1);
                tt += __shfl_xor(tt, 2);
                tt += __shfl_xor(tt, 4);
                tt += __shfl_xor(tt, 8);
                if (c == 0){
                    int grow = r0 + 4*g + j;
                    int b = grow / PP;
                    int p = grow - b*PP;
                    simT[p*32 + b] = tanh_fast(tt + sb4v);   // transposed: simT[p][32]
                }
            }
        }

        if (pf) STAGEW(nxt);                        // overwrite tile buffer (all reads done)
        asm volatile("s_waitcnt vmcnt(0)" ::: "memory");
        __syncthreads();                            // next tile staged (block-wide)
        cur = nxt;
    }
#undef STAGEW
}

// ---------------- KB1: partial c1 = sim @ cw1 (K split 32-ways x 2 halves) ------------
__global__ __launch_bounds__(256) void k_c1(
    const float* __restrict__ simT, const float* __restrict__ cw1,
    float* __restrict__ part)
{
    const int nb = blockIdx.x & 7;        // 8 n-blocks of 128
    const int ks = blockIdx.x >> 3;       // 32 k-splits of 283
    const int t  = threadIdx.x;
    const int n  = nb*128 + (t & 127);
    const int kh = t >> 7;
    const int k0 = ks*283;
    const int k1 = (k0 + 283 < PP) ? k0 + 283 : PP;
    float acc[BB];
    #pragma unroll
    for (int b = 0; b < BB; ++b) acc[b] = 0.f;
    for (int k = k0 + kh; k < k1; k += 2){
        float w = cw1[(size_t)k*1024 + n];
        const float* sp = simT + k*32;    // wave-uniform -> s_loads
        #pragma unroll
        for (int b = 0; b < BB; ++b) acc[b] = fmaf(sp[b], w, acc[b]);
    }
    float* dst = part + (size_t)((ks << 1) | kh) * (BB * 1024) + n;
    #pragma unroll
    for (int b = 0; b < BB; ++b) dst[b*1024] = acc[b];
}

// ---------------- KB2: reduce partials + 1024->256->64->3 + log_softmax ---------------
__global__ __launch_bounds__(256) void k_cls(
    const float* __restrict__ part, const float* __restrict__ cb1,
    const float* __restrict__ cw2,  const float* __restrict__ cb2,
    const float* __restrict__ cw3,  const float* __restrict__ cb3,
    const float* __restrict__ cw4,  const float* __restrict__ cb4,
    float* __restrict__ out)
{
    __shared__ __attribute__((aligned(16))) float c1s[1024];
    __shared__ float c2s[256];
    __shared__ float c3s[64];
    __shared__ float lgs[3];
    const int b = blockIdx.x, t = threadIdx.x;
    #pragma unroll
    for (int i = 0; i < 4; ++i){
        int n = i*256 + t;
        float a = 0.f;
        #pragma unroll 8
        for (int q = 0; q < 64; ++q) a += part[(size_t)q*(BB*1024) + b*1024 + n];
        c1s[n] = fmaxf(a + cb1[n], 0.f);
    }
    __syncthreads();
    {
        float a = cb2[t];
        for (int k = 0; k < 1024; k += 4){
            float4 cv = *reinterpret_cast<const float4*>(&c1s[k]);
            a = fmaf(cv.x, cw2[(k+0)*256 + t], a);
            a = fmaf(cv.y, cw2[(k+1)*256 + t], a);
            a = fmaf(cv.z, cw2[(k+2)*256 + t], a);
            a = fmaf(cv.w, cw2[(k+3)*256 + t], a);
        }
        c2s[t] = fmaxf(a, 0.f);
    }
    __syncthreads();
    if (t < 64){
        float a = cb3[t];
        for (int k = 0; k < 256; ++k) a = fmaf(c2s[k], cw3[k*64 + t], a);
        c3s[t] = fmaxf(a, 0.f);
    }
    __syncthreads();
    if (t < 3){
        float a = cb4[t];
        for (int k = 0; k < 64; ++k) a = fmaf(c3s[k], cw4[k*3 + t], a);
        lgs[t] = a;
    }
    __syncthreads();
    if (t < 3){
        float m = fmaxf(fmaxf(lgs[0], lgs[1]), lgs[2]);
        float s = __expf(lgs[0]-m) + __expf(lgs[1]-m) + __expf(lgs[2]-m);
        out[b*3 + t] = lgs[t] - m - __logf(s);
    }
}

extern "C" void kernel_launch(void* const* d_in, const int* in_sizes, int n_in,
                              void* d_out, int out_size, void* d_ws, size_t ws_size,
                              hipStream_t stream) {
    const float* x   = (const float*)d_in[0];
    const float* sw1 = (const float*)d_in[1];
    const float* sb1 = (const float*)d_in[2];
    const float* sw2 = (const float*)d_in[3];
    const float* sb2 = (const float*)d_in[4];
    const float* sw3 = (const float*)d_in[5];
    const float* sb3 = (const float*)d_in[6];
    const float* sw4 = (const float*)d_in[7];
    const float* sb4 = (const float*)d_in[8];
    const float* cw1 = (const float*)d_in[9];
    const float* cb1 = (const float*)d_in[10];
    const float* cw2 = (const float*)d_in[11];
    const float* cb2 = (const float*)d_in[12];
    const float* cw3 = (const float*)d_in[13];
    const float* cb3 = (const float*)d_in[14];
    const float* cw4 = (const float*)d_in[15];
    const float* cb4 = (const float*)d_in[16];
    (void)in_sizes; (void)n_in; (void)out_size; (void)ws_size;

    char* ws = (char*)d_ws;
    u32x4v* w1f  = (u32x4v*)ws;                        // 48 KB fragment-packed sw1
    float*  simT = (float*)(ws + (64<<10));            // 9045*32 f32 = 1.13 MB
    float*  part = (float*)(ws + (2<<20));             // 64*32*1024 f32 = 8 MB

    k_w1f<<<12, 256, 0, stream>>>(sw1, w1f);
    k_sim<<<NBLK2, 256, 0, stream>>>(x, w1f, sb1, sw2, sb2, sw3, sb3,
                                     sw4, sb4, simT);
    k_c1 <<<256, 256, 0, stream>>>(simT, cw1, part);
    k_cls<<<BB, 256, 0, stream>>>(part, cb1, cw2, cb2, cw3, cb3, cw4, cb4,
                                  (float*)d_out);
}

// Round 8
// 290.071 us; speedup vs baseline: 1.2305x; 1.2305x over previous
//
#include <hip/hip_runtime.h>
#include <stdint.h>
#include <stddef.h>

#define BB 32
#define PP 9045
#define FF 750
#define MM (BB*PP)        // 289440 rows
#define NT16 (MM/16)      // 18090 16-row tiles (exact)

typedef float  f32x4  __attribute__((ext_vector_type(4)));
typedef short  s16x8  __attribute__((ext_vector_type(8)));
typedef unsigned int u32x4v __attribute__((ext_vector_type(4)));

typedef const __attribute__((address_space(1))) void* gp1;
typedef __attribute__((address_space(3))) void* sp3;
typedef __attribute__((address_space(3))) unsigned char* sp3c;

__device__ __forceinline__ unsigned rne_bf16(float f){
    unsigned u = __builtin_bit_cast(unsigned, f);
    return (u + 0x7fffu + ((u >> 16) & 1u)) >> 16;   // round-to-nearest-even
}
__device__ __forceinline__ unsigned pack2(float lo, float hi){
    return rne_bf16(lo) | (rne_bf16(hi) << 16);
}
__device__ __forceinline__ unsigned cvtpk(float lo, float hi){
    unsigned r;
    asm volatile("v_cvt_pk_bf16_f32 %0, %1, %2" : "=v"(r) : "v"(lo), "v"(hi));
    return r;
}
__device__ __forceinline__ float tanh_fast(float v){
    return 1.f - 2.f / (1.f + __expf(2.f * v));
}

// ---------------- K0: pre-pack sw1 (750x32 f32) into MFMA B-fragment layout -----------
// B[k][col] frag for v_mfma_f32_16x16x32_bf16: lane holds col=lane&15, k=8*(lane>>4)+e.
// Index: (s*2+nt)*64 + lane; 24 k-steps (k<768, zero-padded past 750) = 48 KB.
__global__ void k_w1f(const float* __restrict__ sw1, u32x4v* __restrict__ w1f){
    int t = blockIdx.x * blockDim.x + threadIdx.x;   // 0..3071
    if (t >= 24*2*64) return;
    int lane = t & 63, nt = (t >> 6) & 1, s = t >> 7;
    int col = nt*16 + (lane & 15);
    int kb  = s*32 + ((lane >> 4) << 3);
    float v[8];
    #pragma unroll
    for (int e = 0; e < 8; ++e){ int k = kb + e; v[e] = (k < FF) ? sw1[k*32 + col] : 0.f; }
    u32x4v o;
    o.x = pack2(v[0],v[1]); o.y = pack2(v[2],v[3]);
    o.z = pack2(v[4],v[5]); o.w = pack2(v[6],v[7]);
    w1f[t] = o;
}

// ---------------- KA: fused similarity MLP, one wave per 16 rows (R4 structure) -------
// 512-B-per-row burst staging; NEW in R8: NT (non-temporal, CPol bit1 -> aux=2) on the
// x-stream global_load_lds so the 868-MB single-use stream does not allocate in L3/L2.
// w1f/bias loads keep default caching (L2-hot reuse set).
__global__ __launch_bounds__(256, 2) void k_sim(
    const float* __restrict__ x, const u32x4v* __restrict__ w1f,
    const float* __restrict__ sb1,
    const float* __restrict__ sw2, const float* __restrict__ sb2,
    const float* __restrict__ sw3, const float* __restrict__ sb3,
    const float* __restrict__ sw4, const float* __restrict__ sb4,
    float* __restrict__ simT)
{
    __shared__ __attribute__((aligned(16))) unsigned char scratch[4*16384];
    const int wid  = threadIdx.x >> 6;
    const int lane = threadIdx.x & 63;
    const int tile = blockIdx.x*4 + wid;
    if (tile >= NT16) return;            // no __syncthreads in this kernel -> safe
    const int g = lane >> 4;             // k-group
    const int c = lane & 15;             // row (A) / col (B,D)
    const int r0 = tile << 4;
    const unsigned wbase = (unsigned)wid * 16384u;

    // per-lane constant fragments for layers 2/3 + biases
    u32x4v t2, t3;
    {
        float v[8];
        #pragma unroll
        for (int e = 0; e < 8; ++e) v[e] = sw2[(8*g+e)*16 + c];          // sw2: [32][16]
        t2.x = pack2(v[0],v[1]); t2.y = pack2(v[2],v[3]);
        t2.z = pack2(v[4],v[5]); t2.w = pack2(v[6],v[7]);
        #pragma unroll
        for (int e = 0; e < 8; ++e){
            int k = 8*g+e;
            v[e] = (k < 16 && c < 8) ? sw3[k*8 + c] : 0.f;               // sw3: [16][8]
        }
        t3.x = pack2(v[0],v[1]); t3.y = pack2(v[2],v[3]);
        t3.z = pack2(v[4],v[5]); t3.w = pack2(v[6],v[7]);
    }
    const s16x8 w2f = __builtin_bit_cast(s16x8, t2);
    const s16x8 w3f = __builtin_bit_cast(s16x8, t3);
    const float w4c  = (c < 8) ? sw4[c] : 0.f;
    const float sb4v = sb4[0];
    const float b2c  = sb2[c];
    const float b3c  = (c < 8) ? sb3[c] : 0.f;

    f32x4 acc0, acc1;
    { float b0 = sb1[c], b1 = sb1[16+c];
      acc0 = (f32x4){b0,b0,b0,b0}; acc1 = (f32x4){b1,b1,b1,b1}; }

    // ---- staging geometry --------------------------------------------------
    // gll j stages rows {2j, 2j+1}: lane l -> row 2j+(l>>5), 512-B window chunk.
    // LDS (linear dest): buf + 1024j + 16l  ==  buf + row*512 + t, t=16*(l&31).
    // Source pre-swizzled: LDS[row*512+t] = x_row[512q + (t ^ ((row&7)<<4))].
    const int h  = lane >> 5;                       // row-in-pair
    const unsigned t16 = (unsigned)(lane & 31) << 4;
    const char* xb = (const char*)x + (size_t)(r0 + h) * 3000u;

    const uint32_t lbase = (uint32_t)(uintptr_t)(sp3c)scratch + wbase;
    const uint32_t S = ((uint32_t)(c & 7)) << 4;    // read-side swizzle (same involution)

    const unsigned long long wfb = (unsigned long long)(uintptr_t)w1f + (unsigned)lane*16u;

    u32x4v WFA[3][4], WFB[3][4];   // 3 banks x 4 k-steps (static idx only)
    f32x4 D0[4], D1[4];

#define STAGE(QOFF, BUFSEL) do{ \
    _Pragma("unroll") \
    for (int j_ = 0; j_ < 8; ++j_){ \
        unsigned swz_ = t16 ^ ((unsigned)((2*j_ + h) & 7) << 4); \
        __builtin_amdgcn_global_load_lds((gp1)(xb + (QOFF) + 6000*j_ + swz_), \
            (sp3)(scratch + wbase + (unsigned)((BUFSEL)*8192) + (unsigned)(1024*j_)), 16, 0, 2); \
    } \
}while(0)

#define WFLD(Q, B) do{ \
    unsigned long long a_ = wfb + (unsigned)(8192*(Q)); \
    asm volatile("global_load_dwordx4 %0, %1, off"             : "=&v"(WFA[B][0]) : "v"(a_)); \
    asm volatile("global_load_dwordx4 %0, %1, off offset:1024" : "=&v"(WFB[B][0]) : "v"(a_)); \
    asm volatile("global_load_dwordx4 %0, %1, off offset:2048" : "=&v"(WFA[B][1]) : "v"(a_)); \
    asm volatile("global_load_dwordx4 %0, %1, off offset:3072" : "=&v"(WFB[B][1]) : "v"(a_)); \
    unsigned long long a2_ = a_ + 4096u; \
    asm volatile("global_load_dwordx4 %0, %1, off"             : "=&v"(WFA[B][2]) : "v"(a2_)); \
    asm volatile("global_load_dwordx4 %0, %1, off offset:1024" : "=&v"(WFB[B][2]) : "v"(a2_)); \
    asm volatile("global_load_dwordx4 %0, %1, off offset:2048" : "=&v"(WFA[B][3]) : "v"(a2_)); \
    asm volatile("global_load_dwordx4 %0, %1, off offset:3072" : "=&v"(WFB[B][3]) : "v"(a2_)); \
}while(0)

// Window Q: wait counted vmcnt -> 8 swizzled ds_read_b128 -> lgkmcnt(0)+sched_barrier
// -> (refill / tail-fixup in __VA_ARGS__, LDS+reg WAR-safe here) -> 4x pack+2 MFMA.
#define WINDOW(Q, BANK, VMSTR, ...) do{ \
    asm volatile("s_waitcnt vmcnt(" VMSTR ")"); \
    { \
      const uint32_t bb_ = lbase + (uint32_t)(((Q)&1)*8192) + (uint32_t)c*512u; \
      _Pragma("unroll") \
      for (int ks_ = 0; ks_ < 4; ++ks_){ \
          uint32_t u0_ = ((uint32_t)(128*ks_) + 32u*(uint32_t)g) ^ S; \
          uint32_t u1_ = ((uint32_t)(128*ks_) + 32u*(uint32_t)g + 16u) ^ S; \
          asm volatile("ds_read_b128 %0, %1" : "=&v"(D0[ks_]) : "v"(bb_ + u0_)); \
          asm volatile("ds_read_b128 %0, %1" : "=&v"(D1[ks_]) : "v"(bb_ + u1_)); \
      } \
    } \
    asm volatile("s_waitcnt lgkmcnt(0)"); \
    __builtin_amdgcn_sched_barrier(0); \
    __VA_ARGS__ \
    _Pragma("unroll") \
    for (int ks_ = 0; ks_ < 4; ++ks_){ \
        u32x4v a_; \
        a_.x = cvtpk(D0[ks_][0], D0[ks_][1]); a_.y = cvtpk(D0[ks_][2], D0[ks_][3]); \
        a_.z = cvtpk(D1[ks_][0], D1[ks_][1]); a_.w = cvtpk(D1[ks_][2], D1[ks_][3]); \
        s16x8 av_ = __builtin_bit_cast(s16x8, a_); \
        acc0 = __builtin_amdgcn_mfma_f32_16x16x32_bf16(av_, __builtin_bit_cast(s16x8, WFA[BANK][ks_]), acc0, 0,0,0); \
        acc1 = __builtin_amdgcn_mfma_f32_16x16x32_bf16(av_, __builtin_bit_cast(s16x8, WFB[BANK][ks_]), acc1, 0,0,0); \
    } \
}while(0)

    // prologue: ledger (oldest->newest) = S0(8), W0(8), S1(8), W1(8) = 32 outstanding
    STAGE(0,    0); WFLD(0, 0);
    STAGE(512,  1); WFLD(1, 1);

    // 6 windows x 4 k-steps = k 0..767 (750..767 zeroed in registers at window 5).
    // Window 5 over-reads <=72 B past row end (last tile: past x end, within the
    // 4-KB page slack of 868,320,000-byte x -> no fault; data is k>=750 -> zeroed).
    WINDOW(0, 0, "16", STAGE(1024, 0); WFLD(2, 2); );
    WINDOW(1, 1, "16", STAGE(1536, 1); WFLD(3, 0); );
    WINDOW(2, 2, "16", STAGE(2048, 0); WFLD(4, 1); );
    WINDOW(3, 0, "16", STAGE(2560, 1); WFLD(5, 2); );
    WINDOW(4, 1, "16", ; );
    WINDOW(5, 2, "0",
        if (g >= 2){ D0[3] = (f32x4){0.f,0.f,0.f,0.f}; D1[3] = (f32x4){0.f,0.f,0.f,0.f}; }
        else if (g == 1){ D1[3][2] = 0.f; D1[3][3] = 0.f; } );

    asm volatile("" ::: "memory");   // pin epilogue LDS ops below all staging reads

    // ---- layers 2/3/4 via per-wave LDS relayout (reuse buffer 0) -----------
    unsigned short* h1 = (unsigned short*)(scratch + wbase);          // 16x40 bf16
    unsigned short* h2 = (unsigned short*)(scratch + wbase + 2048);   // 16x40 bf16
    for (int i = lane; i < 640; i += 64) h2[i] = 0;  // k=16..31 zero (layer-3 pad)

    #pragma unroll
    for (int j = 0; j < 4; ++j){
        h1[(4*g+j)*40 + c]      = (unsigned short)rne_bf16(fmaxf(acc0[j], 0.f));
        h1[(4*g+j)*40 + 16 + c] = (unsigned short)rne_bf16(fmaxf(acc1[j], 0.f));
    }
    asm volatile("s_waitcnt lgkmcnt(0)" ::: "memory");   // same-wave LDS RAW
    s16x8 a2 = *reinterpret_cast<const s16x8*>(&h1[c*40 + 8*g]);
    f32x4 c2i = {b2c,b2c,b2c,b2c};
    f32x4 d2 = __builtin_amdgcn_mfma_f32_16x16x32_bf16(a2, w2f, c2i, 0,0,0);

    #pragma unroll
    for (int j = 0; j < 4; ++j)
        h2[(4*g+j)*40 + c] = (unsigned short)rne_bf16(fmaxf(d2[j], 0.f));
    asm volatile("s_waitcnt lgkmcnt(0)" ::: "memory");
    s16x8 a3 = *reinterpret_cast<const s16x8*>(&h2[c*40 + 8*g]);
    f32x4 c3i = {b3c,b3c,b3c,b3c};
    f32x4 d3 = __builtin_amdgcn_mfma_f32_16x16x32_bf16(a3, w3f, c3i, 0,0,0);

    // layer 4: per-row dot over 8 cols (cols 8..15 exact zeros), 16-lane butterfly
    #pragma unroll
    for (int j = 0; j < 4; ++j){
        float t = fmaxf(d3[j], 0.f) * w4c;
        t += __shfl_xor(t, 1);
        t += __shfl_xor(t, 2);
        t += __shfl_xor(t, 4);
        t += __shfl_xor(t, 8);
        if (c == 0){
            int grow = r0 + 4*g + j;
            int b = grow / PP;
            int p = grow - b*PP;
            simT[p*32 + b] = tanh_fast(t + sb4v);   // transposed: simT[p][32 subjects]
        }
    }
#undef STAGE
#undef WFLD
#undef WINDOW
}

// ---------------- KB1: partial c1 = sim @ cw1 (K split 32-ways x 2 halves) ------------
__global__ __launch_bounds__(256) void k_c1(
    const float* __restrict__ simT, const float* __restrict__ cw1,
    float* __restrict__ part)
{
    const int nb = blockIdx.x & 7;        // 8 n-blocks of 128
    const int ks = blockIdx.x >> 3;       // 32 k-splits of 283
    const int t  = threadIdx.x;
    const int n  = nb*128 + (t & 127);
    const int kh = t >> 7;
    const int k0 = ks*283;
    const int k1 = (k0 + 283 < PP) ? k0 + 283 : PP;
    float acc[BB];
    #pragma unroll
    for (int b = 0; b < BB; ++b) acc[b] = 0.f;
    for (int k = k0 + kh; k < k1; k += 2){
        float w = cw1[(size_t)k*1024 + n];
        const float* sp = simT + k*32;    // wave-uniform -> s_loads
        #pragma unroll
        for (int b = 0; b < BB; ++b) acc[b] = fmaf(sp[b], w, acc[b]);
    }
    float* dst = part + (size_t)((ks << 1) | kh) * (BB * 1024) + n;
    #pragma unroll
    for (int b = 0; b < BB; ++b) dst[b*1024] = acc[b];
}

// ---------------- KB2: reduce partials + 1024->256->64->3 + log_softmax ---------------
__global__ __launch_bounds__(256) void k_cls(
    const float* __restrict__ part, const float* __restrict__ cb1,
    const float* __restrict__ cw2,  const float* __restrict__ cb2,
    const float* __restrict__ cw3,  const float* __restrict__ cb3,
    const float* __restrict__ cw4,  const float* __restrict__ cb4,
    float* __restrict__ out)
{
    __shared__ __attribute__((aligned(16))) float c1s[1024];
    __shared__ float c2s[256];
    __shared__ float c3s[64];
    __shared__ float lgs[3];
    const int b = blockIdx.x, t = threadIdx.x;
    #pragma unroll
    for (int i = 0; i < 4; ++i){
        int n = i*256 + t;
        float a = 0.f;
        #pragma unroll 8
        for (int q = 0; q < 64; ++q) a += part[(size_t)q*(BB*1024) + b*1024 + n];
        c1s[n] = fmaxf(a + cb1[n], 0.f);
    }
    __syncthreads();
    {
        float a = cb2[t];
        for (int k = 0; k < 1024; k += 4){
            float4 cv = *reinterpret_cast<const float4*>(&c1s[k]);
            a = fmaf(cv.x, cw2[(k+0)*256 + t], a);
            a = fmaf(cv.y, cw2[(k+1)*256 + t], a);
            a = fmaf(cv.z, cw2[(k+2)*256 + t], a);
            a = fmaf(cv.w, cw2[(k+3)*256 + t], a);
        }
        c2s[t] = fmaxf(a, 0.f);
    }
    __syncthreads();
    if (t < 64){
        float a = cb3[t];
        for (int k = 0; k < 256; ++k) a = fmaf(c2s[k], cw3[k*64 + t], a);
        c3s[t] = fmaxf(a, 0.f);
    }
    __syncthreads();
    if (t < 3){
        float a = cb4[t];
        for (int k = 0; k < 64; ++k) a = fmaf(c3s[k], cw4[k*3 + t], a);
        lgs[t] = a;
    }
    __syncthreads();
    if (t < 3){
        float m = fmaxf(fmaxf(lgs[0], lgs[1]), lgs[2]);
        float s = __expf(lgs[0]-m) + __expf(lgs[1]-m) + __expf(lgs[2]-m);
        out[b*3 + t] = lgs[t] - m - __logf(s);
    }
}

extern "C" void kernel_launch(void* const* d_in, const int* in_sizes, int n_in,
                              void* d_out, int out_size, void* d_ws, size_t ws_size,
                              hipStream_t stream) {
    const float* x   = (const float*)d_in[0];
    const float* sw1 = (const float*)d_in[1];
    const float* sb1 = (const float*)d_in[2];
    const float* sw2 = (const float*)d_in[3];
    const float* sb2 = (const float*)d_in[4];
    const float* sw3 = (const float*)d_in[5];
    const float* sb3 = (const float*)d_in[6];
    const float* sw4 = (const float*)d_in[7];
    const float* sb4 = (const float*)d_in[8];
    const float* cw1 = (const float*)d_in[9];
    const float* cb1 = (const float*)d_in[10];
    const float* cw2 = (const float*)d_in[11];
    const float* cb2 = (const float*)d_in[12];
    const float* cw3 = (const float*)d_in[13];
    const float* cb3 = (const float*)d_in[14];
    const float* cw4 = (const float*)d_in[15];
    const float* cb4 = (const float*)d_in[16];
    (void)in_sizes; (void)n_in; (void)out_size; (void)ws_size;

    char* ws = (char*)d_ws;
    u32x4v* w1f  = (u32x4v*)ws;                        // 48 KB fragment-packed sw1
    float*  simT = (float*)(ws + (64<<10));            // 9045*32 f32 = 1.13 MB
    float*  part = (float*)(ws + (2<<20));             // 64*32*1024 f32 = 8 MB

    k_w1f<<<12, 256, 0, stream>>>(sw1, w1f);
    k_sim<<<(NT16 + 3)/4, 256, 0, stream>>>(x, w1f, sb1, sw2, sb2, sw3, sb3,
                                            sw4, sb4, simT);
    k_c1 <<<256, 256, 0, stream>>>(simT, cw1, part);
    k_cls<<<BB, 256, 0, stream>>>(part, cb1, cw2, cb2, cw3, cb3, cw4, cb4,
                                  (float*)d_out);
}